// Round 7
// baseline (231.905 us; speedup 1.0000x reference)
//
#include <hip/hip_runtime.h>

#define NROWS 524288
#define DDIM  64
#define HCENT 256
#define GRID  512
#define CPB   4   // 256-row chunks per block: 512*4*256 = 524288
#define PASSES 2  // DIAGNOSTIC ONLY: run the sweep twice so the rbf_main
                  // dispatch (~47us) exceeds the 77-79us harness fill
                  // dispatches and surfaces in the top-5 counter table.
                  // Pass 2 rewrites identical outputs (idempotent).
                  // Discriminator: pass 2's X re-read is L3-resident
                  // (134MB < 256MB), so dispatch ~94us => issue/latency-
                  // bound; ~70-80us => HBM-path-bound.

typedef _Float16 half8 __attribute__((ext_vector_type(8)));
typedef float    f32x4 __attribute__((ext_vector_type(4)));

#define LOG2E 1.4426950408889634f
#define K2L   2.8853900817779268f   // 2*log2(e)
#define BIASF 80.0f

__device__ __forceinline__ float fast_exp2(float x) {
#if __has_builtin(__builtin_amdgcn_exp2f)
  return __builtin_amdgcn_exp2f(x);
#else
  return exp2f(x);
#endif
}

// Kernel body = EXACT round-4 structure (best measured: 205.0us), so the
// counters map onto the best-known kernel. NUMERICS proven r4/r5/r6:
// single fp16 RNE product; x2/c2/exponent fp32; absmax 3.388e-21.
__device__ __forceinline__ void load_chunk(const float* __restrict__ X, int rowbase,
                                           int c, int q, float4 (&raw)[8]) {
#pragma unroll
  for (int rt = 0; rt < 2; ++rt) {
    const float* rp = X + (rowbase + rt * 16 + c) * DDIM + q * 8;
#pragma unroll
    for (int kc = 0; kc < 2; ++kc) {
      raw[rt * 4 + kc * 2 + 0] = reinterpret_cast<const float4*>(rp + kc * 32)[0];
      raw[rt * 4 + kc * 2 + 1] = reinterpret_cast<const float4*>(rp + kc * 32)[1];
    }
  }
}

__device__ __forceinline__ void convert_chunk(const float4 (&raw)[8],
                                              half8 (&a)[2][2], float (&x2p)[2]) {
#pragma unroll
  for (int rt = 0; rt < 2; ++rt) {
    float part = 0.f;
#pragma unroll
    for (int kc = 0; kc < 2; ++kc) {
      const float4 f0 = raw[rt * 4 + kc * 2 + 0];
      const float4 f1 = raw[rt * 4 + kc * 2 + 1];
      const float xs[8] = {f0.x, f0.y, f0.z, f0.w, f1.x, f1.y, f1.z, f1.w};
      union { _Float16 h[8]; half8 v; } u;
#pragma unroll
      for (int p = 0; p < 8; ++p) {
        part = fmaf(xs[p], xs[p], part);
        u.h[p] = (_Float16)xs[p];   // v_cvt_f16_f32, RNE
      }
      a[rt][kc] = u.v;
    }
    x2p[rt] = part;
  }
}

__device__ __forceinline__ void chunk_body(const float* __restrict__ X, int rowbase,
                                           bool prefetch,
                                           const float4 (&cur)[8], float4 (&nxt)[8],
                                           const half8* __restrict__ BHv,
                                           const float2* __restrict__ CWs,
                                           int lane, int q, int c, float bval,
                                           float* __restrict__ out) {
  if (prefetch) load_chunk(X, rowbase + 256, c, q, nxt);

  half8 a[2][2];
  float x2p[2];
  convert_chunk(cur, a, x2p);

  float psum[2][4] = {{0.f, 0.f, 0.f, 0.f}, {0.f, 0.f, 0.f, 0.f}};
#pragma unroll 2
  for (int ct = 0; ct < 16; ++ct) {
    int idx = ct * 128 + lane;
    half8 bh0 = BHv[idx], bh1 = BHv[idx + 64];
    float2 mw = CWs[ct * 16 + c];
#pragma unroll
    for (int rt = 0; rt < 2; ++rt) {
      f32x4 acc = {0.f, 0.f, 0.f, 0.f};
      acc = __builtin_amdgcn_mfma_f32_16x16x32_f16(a[rt][0], bh0, acc, 0, 0, 0);
      acc = __builtin_amdgcn_mfma_f32_16x16x32_f16(a[rt][1], bh1, acc, 0, 0, 0);
#pragma unroll
      for (int r = 0; r < 4; ++r) {
        float e = fast_exp2(fmaf(acc[r], K2L, mw.x));
        psum[rt][r] = fmaf(e, mw.y, psum[rt][r]);
      }
    }
  }

#pragma unroll
  for (int rt = 0; rt < 2; ++rt) {
    float part = x2p[rt];
    part += __shfl_xor(part, 16, 64);
    part += __shfl_xor(part, 32, 64);
#pragma unroll
    for (int r = 0; r < 4; ++r) {
      float v = psum[rt][r];
      v += __shfl_xor(v, 1, 64);
      v += __shfl_xor(v, 2, 64);
      v += __shfl_xor(v, 4, 64);
      v += __shfl_xor(v, 8, 64);
      float x2row = __shfl(part, q * 4 + r, 64);
      float rowf = fast_exp2(fmaf(-LOG2E, x2row, BIASF));
      psum[rt][r] = fmaf(v, rowf, bval);
    }
    if (c == 0) {
      float4 o = make_float4(psum[rt][0], psum[rt][1], psum[rt][2], psum[rt][3]);
      *reinterpret_cast<float4*>(out + rowbase + rt * 16 + q * 4) = o;
    }
  }
}

__global__ __launch_bounds__(512, 4) void rbf_main(const float* __restrict__ X,
                                                   const float* __restrict__ bptr,
                                                   const float* __restrict__ centers,
                                                   const float* __restrict__ w,
                                                   float* __restrict__ out) {
  __shared__ int4 BH[16 * 2 * 64];
  __shared__ float2 CWs[HCENT];   // (mc, w) per center; mc = -(L*c2 + BIAS)

  const int tid  = threadIdx.x;
  const int wave = tid >> 6;
  const int lane = tid & 63;
  const int q    = lane >> 4;
  const int c    = lane & 15;

  // ---- stage centers (fp16) + compute c2 (8 waves x 4 (ct,kc) pairs) ----
  float c2acc[2] = {0.f, 0.f};
#pragma unroll
  for (int i = 0; i < 4; ++i) {
    int pair = wave * 4 + i;
    int ct = pair >> 1;
    int kc = pair & 1;
    const float* src = centers + (ct * 16 + c) * DDIM + kc * 32 + q * 8;
    float4 f0 = reinterpret_cast<const float4*>(src)[0];
    float4 f1 = reinterpret_cast<const float4*>(src)[1];
    const float xs[8] = {f0.x, f0.y, f0.z, f0.w, f1.x, f1.y, f1.z, f1.w};
    union { _Float16 h[8]; int4 i4; } u;
    float part = 0.f;
#pragma unroll
    for (int p = 0; p < 8; ++p) {
      part = fmaf(xs[p], xs[p], part);
      u.h[p] = (_Float16)xs[p];
    }
    part += __shfl_xor(part, 16, 64);
    part += __shfl_xor(part, 32, 64);
    c2acc[i >> 1] += part;
    BH[pair * 64 + lane] = u.i4;
  }
  if (lane < 16) {
#pragma unroll
    for (int t = 0; t < 2; ++t) {
      int h = (wave * 2 + t) * 16 + lane;
      CWs[h] = make_float2(-fmaf(c2acc[t], LOG2E, BIASF), w[h]);
    }
  }

  float bval = bptr[0];

  __syncthreads();  // LDS read-only hereafter

  const half8* BHv = reinterpret_cast<const half8*>(BH);

  const int rb0 = blockIdx.x * CPB * 256 + wave * 32;

  float4 rawA[8], rawB[8];

#pragma unroll 1
  for (int pass = 0; pass < PASSES; ++pass) {
    load_chunk(X, rb0, c, q, rawA);
    // fully unrolled, statically-indexed double buffer
    chunk_body(X, rb0 + 0 * 256, true,  rawA, rawB, BHv, CWs, lane, q, c, bval, out);
    chunk_body(X, rb0 + 1 * 256, true,  rawB, rawA, BHv, CWs, lane, q, c, bval, out);
    chunk_body(X, rb0 + 2 * 256, true,  rawA, rawB, BHv, CWs, lane, q, c, bval, out);
    chunk_body(X, rb0 + 3 * 256, false, rawB, rawA, BHv, CWs, lane, q, c, bval, out);
  }
}

extern "C" void kernel_launch(void* const* d_in, const int* in_sizes, int n_in,
                              void* d_out, int out_size, void* d_ws, size_t ws_size,
                              hipStream_t stream) {
  const float* X       = (const float*)d_in[0];
  const float* centers = (const float*)d_in[1];
  const float* w       = (const float*)d_in[2];
  const float* b       = (const float*)d_in[3];
  float* out = (float*)d_out;
  (void)d_ws; (void)ws_size;   // workspace unused: setup fused into rbf_main

  rbf_main<<<GRID, 512, 0, stream>>>(X, b, centers, w, out);
}

// Round 8
// 202.671 us; speedup vs baseline: 1.1442x; 1.1442x over previous
//
#include <hip/hip_runtime.h>

#define NROWS 524288
#define DDIM  64
#define HCENT 256
// ROUND 8: GRID 512 -> 1024, CPB 4 -> 2. r7 diagnostic measured VGPR=64,
// LDS=34816 => 4 blocks/CU fit (139KB/160KB LDS, 8 waves/SIMD by VGPR),
// but GRID=512 only ever made 2 blocks/CU resident. Counters showed
// VALUBusy 33% / MfmaUtil 13% / HBM 12% / occupancy 32% and an L3-resident
// second pass ran NO faster => issue/latency-bound, needs cross-wave
// overlap, i.e. more resident blocks. 1024 blocks = 4/CU. Extra cost: one
// more center-staging per CU pair (~1-2us total).
#define GRID  1024
#define CPB   2   // 256-row chunks per block: 1024*2*256 = 524288

typedef _Float16 half8 __attribute__((ext_vector_type(8)));
typedef float    f32x4 __attribute__((ext_vector_type(4)));

#define LOG2E 1.4426950408889634f
#define K2L   2.8853900817779268f   // 2*log2(e)
#define BIASF 80.0f

__device__ __forceinline__ float fast_exp2(float x) {
#if __has_builtin(__builtin_amdgcn_exp2f)
  return __builtin_amdgcn_exp2f(x);
#else
  return exp2f(x);
#endif
}

// NUMERICS (proven r4-r7, absmax 3.388132e-21 vs 9.62e-21 threshold):
// single fp16 RNE product; x2/c2/exponent fp32; c2 in-block fp32 tree-sum;
// centers NOT pre-scaled before rounding (r2 fail); NOT single-bf16 (r1/r2
// marginal/fail). Body = exact r4/r7 structure (VGPR=64 measured).
__device__ __forceinline__ void load_chunk(const float* __restrict__ X, int rowbase,
                                           int c, int q, float4 (&raw)[8]) {
#pragma unroll
  for (int rt = 0; rt < 2; ++rt) {
    const float* rp = X + (rowbase + rt * 16 + c) * DDIM + q * 8;
#pragma unroll
    for (int kc = 0; kc < 2; ++kc) {
      raw[rt * 4 + kc * 2 + 0] = reinterpret_cast<const float4*>(rp + kc * 32)[0];
      raw[rt * 4 + kc * 2 + 1] = reinterpret_cast<const float4*>(rp + kc * 32)[1];
    }
  }
}

__device__ __forceinline__ void convert_chunk(const float4 (&raw)[8],
                                              half8 (&a)[2][2], float (&x2p)[2]) {
#pragma unroll
  for (int rt = 0; rt < 2; ++rt) {
    float part = 0.f;
#pragma unroll
    for (int kc = 0; kc < 2; ++kc) {
      const float4 f0 = raw[rt * 4 + kc * 2 + 0];
      const float4 f1 = raw[rt * 4 + kc * 2 + 1];
      const float xs[8] = {f0.x, f0.y, f0.z, f0.w, f1.x, f1.y, f1.z, f1.w};
      union { _Float16 h[8]; half8 v; } u;
#pragma unroll
      for (int p = 0; p < 8; ++p) {
        part = fmaf(xs[p], xs[p], part);
        u.h[p] = (_Float16)xs[p];   // v_cvt_f16_f32, RNE
      }
      a[rt][kc] = u.v;
    }
    x2p[rt] = part;
  }
}

__device__ __forceinline__ void chunk_body(const float* __restrict__ X, int rowbase,
                                           bool prefetch,
                                           const float4 (&cur)[8], float4 (&nxt)[8],
                                           const half8* __restrict__ BHv,
                                           const float2* __restrict__ CWs,
                                           int lane, int q, int c, float bval,
                                           float* __restrict__ out) {
  if (prefetch) load_chunk(X, rowbase + 256, c, q, nxt);

  half8 a[2][2];
  float x2p[2];
  convert_chunk(cur, a, x2p);

  float psum[2][4] = {{0.f, 0.f, 0.f, 0.f}, {0.f, 0.f, 0.f, 0.f}};
#pragma unroll 2
  for (int ct = 0; ct < 16; ++ct) {
    int idx = ct * 128 + lane;
    half8 bh0 = BHv[idx], bh1 = BHv[idx + 64];
    float2 mw = CWs[ct * 16 + c];
#pragma unroll
    for (int rt = 0; rt < 2; ++rt) {
      f32x4 acc = {0.f, 0.f, 0.f, 0.f};
      acc = __builtin_amdgcn_mfma_f32_16x16x32_f16(a[rt][0], bh0, acc, 0, 0, 0);
      acc = __builtin_amdgcn_mfma_f32_16x16x32_f16(a[rt][1], bh1, acc, 0, 0, 0);
#pragma unroll
      for (int r = 0; r < 4; ++r) {
        float e = fast_exp2(fmaf(acc[r], K2L, mw.x));
        psum[rt][r] = fmaf(e, mw.y, psum[rt][r]);
      }
    }
  }

#pragma unroll
  for (int rt = 0; rt < 2; ++rt) {
    float part = x2p[rt];
    part += __shfl_xor(part, 16, 64);
    part += __shfl_xor(part, 32, 64);
#pragma unroll
    for (int r = 0; r < 4; ++r) {
      float v = psum[rt][r];
      v += __shfl_xor(v, 1, 64);
      v += __shfl_xor(v, 2, 64);
      v += __shfl_xor(v, 4, 64);
      v += __shfl_xor(v, 8, 64);
      float x2row = __shfl(part, q * 4 + r, 64);
      float rowf = fast_exp2(fmaf(-LOG2E, x2row, BIASF));
      psum[rt][r] = fmaf(v, rowf, bval);
    }
    if (c == 0) {
      float4 o = make_float4(psum[rt][0], psum[rt][1], psum[rt][2], psum[rt][3]);
      *reinterpret_cast<float4*>(out + rowbase + rt * 16 + q * 4) = o;
    }
  }
}

__global__ __launch_bounds__(512, 4) void rbf_main(const float* __restrict__ X,
                                                   const float* __restrict__ bptr,
                                                   const float* __restrict__ centers,
                                                   const float* __restrict__ w,
                                                   float* __restrict__ out) {
  // Fragment-ordered for conflict-free ds_read_b128: index = (ct*2+kc)*64+lane
  __shared__ int4 BH[16 * 2 * 64];
  __shared__ float2 CWs[HCENT];   // (mc, w) per center; mc = -(L*c2 + BIAS)

  const int tid  = threadIdx.x;
  const int wave = tid >> 6;
  const int lane = tid & 63;
  const int q    = lane >> 4;
  const int c    = lane & 15;

  // ---- stage centers (fp16) + compute c2 (8 waves x 4 (ct,kc) pairs) ----
  float c2acc[2] = {0.f, 0.f};
#pragma unroll
  for (int i = 0; i < 4; ++i) {
    int pair = wave * 4 + i;
    int ct = pair >> 1;
    int kc = pair & 1;
    const float* src = centers + (ct * 16 + c) * DDIM + kc * 32 + q * 8;
    float4 f0 = reinterpret_cast<const float4*>(src)[0];
    float4 f1 = reinterpret_cast<const float4*>(src)[1];
    const float xs[8] = {f0.x, f0.y, f0.z, f0.w, f1.x, f1.y, f1.z, f1.w};
    union { _Float16 h[8]; int4 i4; } u;
    float part = 0.f;
#pragma unroll
    for (int p = 0; p < 8; ++p) {
      part = fmaf(xs[p], xs[p], part);
      u.h[p] = (_Float16)xs[p];
    }
    part += __shfl_xor(part, 16, 64);
    part += __shfl_xor(part, 32, 64);
    c2acc[i >> 1] += part;
    BH[pair * 64 + lane] = u.i4;
  }
  if (lane < 16) {
#pragma unroll
    for (int t = 0; t < 2; ++t) {
      int h = (wave * 2 + t) * 16 + lane;
      CWs[h] = make_float2(-fmaf(c2acc[t], LOG2E, BIASF), w[h]);
    }
  }

  float bval = bptr[0];

  __syncthreads();  // LDS read-only hereafter

  const half8* BHv = reinterpret_cast<const half8*>(BH);

  const int rb0 = blockIdx.x * CPB * 256 + wave * 32;

  float4 rawA[8], rawB[8];
  load_chunk(X, rb0, c, q, rawA);

  // fully unrolled, statically-indexed double buffer (CPB=2)
  chunk_body(X, rb0 + 0 * 256, true,  rawA, rawB, BHv, CWs, lane, q, c, bval, out);
  chunk_body(X, rb0 + 1 * 256, false, rawB, rawA, BHv, CWs, lane, q, c, bval, out);
}

extern "C" void kernel_launch(void* const* d_in, const int* in_sizes, int n_in,
                              void* d_out, int out_size, void* d_ws, size_t ws_size,
                              hipStream_t stream) {
  const float* X       = (const float*)d_in[0];
  const float* centers = (const float*)d_in[1];
  const float* w       = (const float*)d_in[2];
  const float* b       = (const float*)d_in[3];
  float* out = (float*)d_out;
  (void)d_ws; (void)ws_size;   // workspace unused: setup fused into rbf_main

  rbf_main<<<GRID, 512, 0, stream>>>(X, b, centers, w, out);
}